// Round 1
// 267.504 us; speedup vs baseline: 1.0226x; 1.0226x over previous
//
#include <hip/hip_runtime.h>
#include <hip/hip_bf16.h>

// B=4, N=2048, C=768, H=16, D=48. FP32 in/out.
// Pipeline: cvt(x,W->bf16) -> gemm_qkv (fused, global_load_lds) -> qkv_reshape
//           -> attn (all-register P via cvt_pk+permlane32_swap, 32x32 PV with
//              ones-row L fused) -> gemm_out.
#define B_ 4
#define N_ 2048
#define C_ 768
#define H_ 16
#define D_ 48
#define SCALE_ 0.14433756729740643f
#define LOG2E_ 1.44269504088896f

using bf16 = __hip_bfloat16;
using bf16x8 = __attribute__((ext_vector_type(8))) short;
using f32x4  = __attribute__((ext_vector_type(4))) float;
using f32x16 = __attribute__((ext_vector_type(16))) float;
using u32x2  = __attribute__((ext_vector_type(2))) unsigned int;
using u32x4  = __attribute__((ext_vector_type(4))) unsigned int;

__device__ __forceinline__ unsigned short f2b(float f) {
  bf16 h = __float2bfloat16(f);
  return *reinterpret_cast<unsigned short*>(&h);
}
__device__ __forceinline__ unsigned int pack2(float lo, float hi) {
  return (unsigned int)f2b(lo) | ((unsigned int)f2b(hi) << 16);
}
// packed f32->bf16 (RNE), single instruction
__device__ __forceinline__ unsigned int pk2(float lo, float hi) {
  unsigned int r;
  asm("v_cvt_pk_bf16_f32 %0, %1, %2" : "=v"(r) : "v"(lo), "v"(hi));
  return r;
}
__device__ __forceinline__ uint4 ld8f_cvt(const float* p) {
  float4 a = *reinterpret_cast<const float4*>(p);
  float4 b = *reinterpret_cast<const float4*>(p + 4);
  uint4 u;
  u.x = pack2(a.x, a.y); u.y = pack2(a.z, a.w);
  u.z = pack2(b.x, b.y); u.w = pack2(b.z, b.w);
  return u;
}
// async global->LDS, 16B per lane; LDS dest = l + lane*16B (wave-uniform base)
__device__ __forceinline__ void gload_lds16(const bf16* g, bf16* l) {
  __builtin_amdgcn_global_load_lds(
      (const __attribute__((address_space(1))) unsigned int*)g,
      (__attribute__((address_space(3))) unsigned int*)l, 16, 0, 0);
}

// ---- Kernel 0: fp32 -> bf16 conversions (x, Wq|Wk|Wv stacked, Wo).
__global__ __launch_bounds__(256) void cvt_bf16(
    const float* __restrict__ x,  const float* __restrict__ wq,
    const float* __restrict__ wk, const float* __restrict__ wv,
    const float* __restrict__ wo,
    bf16* __restrict__ xb, bf16* __restrict__ wqkvb, bf16* __restrict__ wob)
{
  const int job = blockIdx.y;
  const float* src; bf16* dst; int n;
  if (job == 0)      { src = x;  dst = xb;              n = B_ * N_ * C_; }
  else if (job == 1) { src = wq; dst = wqkvb;           n = C_ * C_; }
  else if (job == 2) { src = wk; dst = wqkvb + C_ * C_; n = C_ * C_; }
  else if (job == 3) { src = wv; dst = wqkvb + 2 * C_ * C_; n = C_ * C_; }
  else               { src = wo; dst = wob;             n = C_ * C_; }
  const int stride = gridDim.x * 256 * 8;
  for (int i = (blockIdx.x * 256 + threadIdx.x) * 8; i < n; i += stride)
    *(uint4*)(dst + i) = ld8f_cvt(src + i);
}

// ---- Kernel 1: fused QKV GEMM, m97-style. A=xb[8192x768], B=Wqkv[2304x768].
// 128x128 tile, BK=64, global_load_lds staging, XOR-swizzled LDS chunks.
// z = blockIdx.x/6 selects Q/K/V dst (writes [b][h][n][48], Q scaled).
__global__ __launch_bounds__(256) void gemm_qkv(
    const bf16* __restrict__ A, const bf16* __restrict__ Bw,
    const float* __restrict__ bq, const float* __restrict__ bk,
    const float* __restrict__ bv,
    bf16* __restrict__ Q, bf16* __restrict__ K, bf16* __restrict__ V)
{
  __shared__ __align__(16) bf16 As[128 * 64];
  __shared__ __align__(16) bf16 Bs[128 * 64];

  const int tid  = threadIdx.x;
  const int lane = tid & 63, wid = tid >> 6;
  const int wm = (wid >> 1) * 64, wn = (wid & 1) * 64;
  const int row0 = blockIdx.y * 128, col0 = blockIdx.x * 128;
  const int mb = lane & 15, g4 = lane >> 4;
  const int srow = lane >> 3;                    // staging row-in-8
  const int schunk = (lane & 7) ^ (srow & 7);    // swizzled glb k-chunk

  f32x4 acc[4][4];
#pragma unroll
  for (int i = 0; i < 4; ++i)
#pragma unroll
    for (int j = 0; j < 4; ++j) acc[i][j] = (f32x4){0.f, 0.f, 0.f, 0.f};

  for (int k0 = 0; k0 < C_; k0 += 64) {
#pragma unroll
    for (int t = 0; t < 4; ++t) {
      const int rt = wid * 32 + t * 8;
      gload_lds16(A  + (size_t)(row0 + rt + srow) * C_ + k0 + schunk * 8,
                  As + rt * 64);
      gload_lds16(Bw + (size_t)(col0 + rt + srow) * C_ + k0 + schunk * 8,
                  Bs + rt * 64);
    }
    __syncthreads();
#pragma unroll
    for (int ks = 0; ks < 2; ++ks) {
      const int kchunk = ks * 4 + g4;
      bf16x8 af[4], bfr[4];
#pragma unroll
      for (int i = 0; i < 4; ++i) {
        const int row = wm + i * 16 + mb;
        af[i] = *(const bf16x8*)(As + row * 64 + (kchunk ^ (row & 7)) * 8);
      }
#pragma unroll
      for (int j = 0; j < 4; ++j) {
        const int col = wn + j * 16 + mb;
        bfr[j] = *(const bf16x8*)(Bs + col * 64 + (kchunk ^ (col & 7)) * 8);
      }
#pragma unroll
      for (int i = 0; i < 4; ++i)
#pragma unroll
        for (int j = 0; j < 4; ++j)
          acc[i][j] = __builtin_amdgcn_mfma_f32_16x16x32_bf16(af[i], bfr[j], acc[i][j], 0, 0, 0);
    }
    __syncthreads();
  }

  const int z = blockIdx.x / 6;                  // 768/128=6 blocks per proj
  const float* bias = (z == 0) ? bq : (z == 1) ? bk : bv;
  bf16* dst = (z == 0) ? Q : (z == 1) ? K : V;
  const float sc = (z == 0) ? (SCALE_ * LOG2E_) : 1.0f;
  const int crow = g4 * 4;
#pragma unroll
  for (int j = 0; j < 4; ++j) {
    const int oo = col0 - z * 768 + wn + j * 16 + mb;
    const int h = oo / D_, d = oo % D_;
    const float bb = bias[oo];
#pragma unroll
    for (int i = 0; i < 4; ++i) {
#pragma unroll
      for (int reg = 0; reg < 4; ++reg) {
        const int r = row0 + wm + i * 16 + crow + reg;
        const int b_ = r >> 11, n = r & (N_ - 1);
        dst[(((size_t)(b_ * H_ + h)) * N_ + n) * D_ + d] =
            __float2bfloat16((acc[i][j][reg] + bb) * sc);
      }
    }
  }
}

// ---- Kernel 1b: reshape Q,K (in-place) into 32x32 MFMA A/B fragment layout;
// V (from Vtmp) into padded 32x32 A-operand layout Vf[bh][N/16][2][64][8]:
//   element (ksg, dt, l, e) = V[n = ksg*16 + (l>>5)*8 + e][d = dt*32 + (l&31)]
//   dt=1 pad: (l&31)==16 -> 1.0 (fused L row-sum row), (l&31)>16 -> 0.
__global__ __launch_bounds__(256) void qkv_reshape(
    bf16* __restrict__ Q, bf16* __restrict__ K,
    const bf16* __restrict__ Vtmp, bf16* __restrict__ Vf)
{
  __shared__ short T[64 * 50];
  const int bh = blockIdx.x;
  const int t0 = blockIdx.y * 64;
  const int tid = threadIdx.x;
  const size_t base = (size_t)bh * (N_ * D_) + (size_t)t0 * D_;
#pragma unroll 1
  for (int wbuf = 0; wbuf < 2; ++wbuf) {
    bf16* P = (wbuf ? K : Q) + base;
    for (int cc = tid; cc < 384; cc += 256) {
      const int r = cc / 6, ch = cc % 6;
      bf16x8 v8 = *(const bf16x8*)(P + r * D_ + ch * 8);
#pragma unroll
      for (int e = 0; e < 8; ++e) T[r * 50 + ch * 8 + e] = v8[e];
    }
    __syncthreads();
    for (int w = tid; w < 384; w += 256) {
      const int sub = w / 192, rem = w % 192;
      const int kc = rem / 64, rem2 = rem % 64;
      const int g2 = rem2 >> 5, m5 = rem2 & 31;
      bf16x8 o;
#pragma unroll
      for (int e = 0; e < 8; ++e)
        o[e] = T[(sub * 32 + m5) * 50 + kc * 16 + g2 * 8 + e];
      *(bf16x8*)(P + w * 8) = o;
    }
    __syncthreads();
  }
  // V: Vtmp [bh][n][48] -> Vf padded fragment layout
  {
    const bf16* Pv = Vtmp + base;
    for (int cc = tid; cc < 384; cc += 256) {
      const int r = cc / 6, ch = cc % 6;
      bf16x8 v8 = *(const bf16x8*)(Pv + r * D_ + ch * 8);
#pragma unroll
      for (int e = 0; e < 8; ++e) T[r * 50 + ch * 8 + e] = v8[e];
    }
    __syncthreads();
    bf16* W = Vf + (size_t)bh * (N_ * 64) + (size_t)t0 * 64;
    for (int w = tid; w < 512; w += 256) {
      const int ksl = w >> 7;            // 0..3 (K16 group)
      const int dt  = (w >> 6) & 1;      // d-tile
      const int l   = w & 63;
      const int hi = l >> 5, m5 = l & 31;
      bf16x8 o;
      if (dt == 0) {
#pragma unroll
        for (int e = 0; e < 8; ++e)
          o[e] = T[(ksl * 16 + hi * 8 + e) * 50 + m5];
      } else if (m5 < 16) {
#pragma unroll
        for (int e = 0; e < 8; ++e)
          o[e] = T[(ksl * 16 + hi * 8 + e) * 50 + 32 + m5];
      } else {
        const short fill = (m5 == 16) ? (short)0x3F80 : (short)0;
#pragma unroll
        for (int e = 0; e < 8; ++e) o[e] = fill;
      }
      *(bf16x8*)(W + (size_t)(((ksl * 2 + dt) * 64 + l) * 8)) = o;
    }
  }
}

// ---- Kernel 2: zero-LDS register flash attention.
// QK^T: st = mfma32x32(K,Q) -> lane holds P[q=lane&31][16 k-rows] per mt.
// P->bf16 B-fragments fully in-register: 4x cvt_pk + 2x permlane32_swap per
// K16-step. PV: O^T = mfma32x32(V^T_frag, P_frag); V d-tile 1 carries a
// ones-row at row 16 so L (row-sum) falls out of the same MFMAs.
__global__ __launch_bounds__(256) void attn_mfma(
    const bf16* __restrict__ Qf, const bf16* __restrict__ Kf,
    const bf16* __restrict__ Vf, const float* __restrict__ x,
    bf16* __restrict__ Yb)
{
  const int tid  = threadIdx.x;
  const int lane = tid & 63, wid = tid >> 6;
  const int m5 = lane & 31, hi = lane >> 5;
  const int bh = blockIdx.x;
  const int b_ = bh >> 4, h = bh & 15;
  const int q0 = blockIdx.y * 128 + wid * 32;
  const size_t slab  = (size_t)bh * (N_ * D_);
  const size_t slabV = (size_t)bh * (N_ * 64);

  bf16x8 qf[3];
  const int kgq = q0 >> 5;
#pragma unroll
  for (int kc = 0; kc < 3; ++kc)
    qf[kc] = *(const bf16x8*)(Qf + slab + (size_t)(((kgq * 3 + kc) * 64) + lane) * 8);

  f32x16 Oacc[2];
#pragma unroll
  for (int dt = 0; dt < 2; ++dt)
#pragma unroll
    for (int r = 0; r < 16; ++r) Oacc[dt][r] = 0.f;

  bf16x8 kf[2][2][3];
  auto loadK = [&](int kk0, int p) {
    const int kg = kk0 >> 5;
#pragma unroll
    for (int mt = 0; mt < 2; ++mt)
#pragma unroll
      for (int kc = 0; kc < 3; ++kc)
        kf[p][mt][kc] = *(const bf16x8*)(Kf + slab +
            (size_t)((((kg + mt) * 3 + kc) * 64) + lane) * 8);
  };
  auto body = [&](int k0c, int p) {
    const int kg16 = k0c >> 4;
    bf16x8 vA[4][2];
#pragma unroll
    for (int ks = 0; ks < 4; ++ks)
#pragma unroll
      for (int dt = 0; dt < 2; ++dt)
        vA[ks][dt] = *(const bf16x8*)(Vf + slabV +
            (size_t)((((kg16 + ks) * 2 + dt) * 64) + lane) * 8);
    f32x16 st[2];
#pragma unroll
    for (int mt = 0; mt < 2; ++mt) {
      f32x16 z;
#pragma unroll
      for (int r = 0; r < 16; ++r) z[r] = 0.f;
      st[mt] = __builtin_amdgcn_mfma_f32_32x32x16_bf16(kf[p][mt][0], qf[0], z, 0, 0, 0);
      st[mt] = __builtin_amdgcn_mfma_f32_32x32x16_bf16(kf[p][mt][1], qf[1], st[mt], 0, 0, 0);
      st[mt] = __builtin_amdgcn_mfma_f32_32x32x16_bf16(kf[p][mt][2], qf[2], st[mt], 0, 0, 0);
    }
#pragma unroll
    for (int mt = 0; mt < 2; ++mt)
#pragma unroll
      for (int r = 0; r < 16; ++r)
        st[mt][r] = __builtin_amdgcn_exp2f(st[mt][r]);
    // st[mt] reg 4*qq+rr = P[q=lane&31][k32 = rr + 8*qq + 4*hi] (k = mt*32+k32)
    // build B-fragment for each K16 step: lane(q,hi') holds k = 8*hi' + 0..7
#pragma unroll
    for (int ks = 0; ks < 4; ++ks) {
      const f32x16& S = st[ks >> 1];
      const int qa = (ks & 1) * 2;
      const unsigned A0 = pk2(S[4 * qa + 0], S[4 * qa + 1]);
      const unsigned A1 = pk2(S[4 * qa + 2], S[4 * qa + 3]);
      const unsigned B0 = pk2(S[4 * qa + 4], S[4 * qa + 5]);
      const unsigned B1 = pk2(S[4 * qa + 6], S[4 * qa + 7]);
      const u32x2 r02 = __builtin_amdgcn_permlane32_swap(A0, B0, false, false);
      const u32x2 r13 = __builtin_amdgcn_permlane32_swap(A1, B1, false, false);
      u32x4 pw;
      pw.x = r02.x; pw.y = r13.x; pw.z = r02.y; pw.w = r13.y;
      const bf16x8 pb = (bf16x8)pw;
      Oacc[0] = __builtin_amdgcn_mfma_f32_32x32x16_bf16(vA[ks][0], pb, Oacc[0], 0, 0, 0);
      Oacc[1] = __builtin_amdgcn_mfma_f32_32x32x16_bf16(vA[ks][1], pb, Oacc[1], 0, 0, 0);
    }
  };

  loadK(0, 0);
  for (int k0 = 0; k0 < N_; k0 += 128) {
    loadK(k0 + 64, 1);
    body(k0, 0);
    if (k0 + 128 < N_) loadK(k0 + 128, 0);
    body(k0 + 64, 1);
  }

  // L[q] lives in Oacc[1] row 16 = reg 8 of hi=0 lanes; broadcast to hi=1.
  const float lf = Oacc[1][8];
  const unsigned lu = __builtin_bit_cast(unsigned, lf);
  const u32x2 lsw = __builtin_amdgcn_permlane32_swap(lu, lu, false, false);
  const float Lv = __builtin_bit_cast(float, lsw.x);
  const float inv = 1.f / Lv;

  const int n = q0 + m5;
  const size_t rowoff = ((size_t)(b_ * N_ + n)) * C_ + h * D_;
#pragma unroll
  for (int qq = 0; qq < 4; ++qq) {
    const size_t off = rowoff + 8 * qq + 4 * hi;      // d = 8qq+4hi .. +3
    const float4 xr = *(const float4*)(x + off);
    u32x2 wv;
    wv.x = pk2(Oacc[0][4 * qq + 0] * inv + xr.x, Oacc[0][4 * qq + 1] * inv + xr.y);
    wv.y = pk2(Oacc[0][4 * qq + 2] * inv + xr.z, Oacc[0][4 * qq + 3] * inv + xr.w);
    *(u32x2*)(Yb + off) = wv;
  }
#pragma unroll
  for (int qq = 0; qq < 2; ++qq) {
    const size_t off = rowoff + 32 + 8 * qq + 4 * hi; // d = 32+8qq+4hi .. +3
    const float4 xr = *(const float4*)(x + off);
    u32x2 wv;
    wv.x = pk2(Oacc[1][4 * qq + 0] * inv + xr.x, Oacc[1][4 * qq + 1] * inv + xr.y);
    wv.y = pk2(Oacc[1][4 * qq + 2] * inv + xr.z, Oacc[1][4 * qq + 3] * inv + xr.w);
    *(u32x2*)(Yb + off) = wv;
  }
}

// ---- Kernel 3: O projection + residuals, m97-style staging.
// out[r][o] = acc + bo[o] + float(Yb[r][o]) + x[r][o]
__global__ __launch_bounds__(256) void gemm_out(
    const bf16* __restrict__ Yb, const bf16* __restrict__ Bw,
    const float* __restrict__ bo, const float* __restrict__ x,
    float* __restrict__ out)
{
  __shared__ __align__(16) bf16 As[128 * 64];
  __shared__ __align__(16) bf16 Bs[128 * 64];

  const int tid  = threadIdx.x;
  const int lane = tid & 63, wid = tid >> 6;
  const int wm = (wid >> 1) * 64, wn = (wid & 1) * 64;
  const int row0 = blockIdx.y * 128, col0 = blockIdx.x * 128;
  const int mb = lane & 15, g4 = lane >> 4;
  const int srow = lane >> 3;
  const int schunk = (lane & 7) ^ (srow & 7);

  f32x4 acc[4][4];
#pragma unroll
  for (int i = 0; i < 4; ++i)
#pragma unroll
    for (int j = 0; j < 4; ++j) acc[i][j] = (f32x4){0.f, 0.f, 0.f, 0.f};

  for (int k0 = 0; k0 < C_; k0 += 64) {
#pragma unroll
    for (int t = 0; t < 4; ++t) {
      const int rt = wid * 32 + t * 8;
      gload_lds16(Yb + (size_t)(row0 + rt + srow) * C_ + k0 + schunk * 8,
                  As + rt * 64);
      gload_lds16(Bw + (size_t)(col0 + rt + srow) * C_ + k0 + schunk * 8,
                  Bs + rt * 64);
    }
    __syncthreads();
#pragma unroll
    for (int ks = 0; ks < 2; ++ks) {
      const int kchunk = ks * 4 + g4;
      bf16x8 af[4], bfr[4];
#pragma unroll
      for (int i = 0; i < 4; ++i) {
        const int row = wm + i * 16 + mb;
        af[i] = *(const bf16x8*)(As + row * 64 + (kchunk ^ (row & 7)) * 8);
      }
#pragma unroll
      for (int j = 0; j < 4; ++j) {
        const int col = wn + j * 16 + mb;
        bfr[j] = *(const bf16x8*)(Bs + col * 64 + (kchunk ^ (col & 7)) * 8);
      }
#pragma unroll
      for (int i = 0; i < 4; ++i)
#pragma unroll
        for (int j = 0; j < 4; ++j)
          acc[i][j] = __builtin_amdgcn_mfma_f32_16x16x32_bf16(af[i], bfr[j], acc[i][j], 0, 0, 0);
    }
    __syncthreads();
  }

  const int crow = g4 * 4;
#pragma unroll
  for (int j = 0; j < 4; ++j) {
    const int o = col0 + wn + j * 16 + mb;
    const float bb = bo[o];
#pragma unroll
    for (int i = 0; i < 4; ++i) {
#pragma unroll
      for (int reg = 0; reg < 4; ++reg) {
        const int r = row0 + wm + i * 16 + crow + reg;
        const size_t off = (size_t)r * C_ + o;
        out[off] = acc[i][j][reg] + bb + __bfloat162float(Yb[off]) + x[off];
      }
    }
  }
}

extern "C" void kernel_launch(void* const* d_in, const int* in_sizes, int n_in,
                              void* d_out, int out_size, void* d_ws, size_t ws_size,
                              hipStream_t stream)
{
  const float* x  = (const float*)d_in[0];
  const float* wq = (const float*)d_in[1];
  const float* bq = (const float*)d_in[2];
  const float* wk = (const float*)d_in[3];
  const float* bk = (const float*)d_in[4];
  const float* wv = (const float*)d_in[5];
  const float* bv = (const float*)d_in[6];
  const float* wo = (const float*)d_in[7];
  const float* bo = (const float*)d_in[8];
  float* out = (float*)d_out;

  const size_t nEl  = (size_t)B_ * N_ * C_;     // 6,291,456
  const size_t wEl  = (size_t)C_ * C_;          // 589,824
  const size_t vfEl = (size_t)B_ * H_ * N_ * 64; // 8,388,608 (padded V frags)
  bf16* Q     = (bf16*)d_ws;                    // fragment layout after reshape
  bf16* K     = Q + nEl;
  bf16* Vf    = K + nEl;                        // padded V A-fragment layout
  bf16* Yb    = Vf + vfEl;                      // Vtmp before attn; then y=attn+x
  bf16* xb    = Yb + nEl;                       // [8192][768] bf16
  bf16* wqkvb = xb + nEl;                       // [2304][768] bf16 stacked
  bf16* wob   = wqkvb + 3 * wEl;                // [768][768] bf16

  dim3 gcvt(768, 5);
  cvt_bf16<<<gcvt, dim3(256), 0, stream>>>(x, wq, wk, wv, wo, xb, wqkvb, wob);

  dim3 gqkv(18, 64);                            // 2304/128 x 8192/128
  gemm_qkv<<<gqkv, dim3(256), 0, stream>>>(xb, wqkvb, bq, bk, bv, Q, K, Yb);

  dim3 grs(B_ * H_, N_ / 64);                   // Q,K in-place; V: Yb -> Vf
  qkv_reshape<<<grs, dim3(256), 0, stream>>>(Q, K, Yb, Vf);

  dim3 gattn(B_ * H_, N_ / 128);                // (64, 16)
  attn_mfma<<<gattn, dim3(256), 0, stream>>>(Q, K, Vf, x, Yb);

  dim3 gout(6, 64);                             // 768/128 x 8192/128
  gemm_out<<<gout, dim3(256), 0, stream>>>(Yb, wob, bo, x, out);
}